// Round 1
// baseline (34705.264 us; speedup 1.0000x reference)
//
#include <hip/hip_runtime.h>

#define B_SZ    64
#define T_STEPS 512
#define U1      128
#define S1      128
#define U2      256
#define S2      128
#define NUNF    6

__device__ __forceinline__ float fast_exp2(float x) { return __builtin_amdgcn_exp2f(x); }
__device__ __forceinline__ float fast_rcp(float x)  { return __builtin_amdgcn_rcpf(x); }

// ---------------------------------------------------------------------------
// Param transform: A = sigma*log2(e), B = mu*sigma*log2(e), W = w*erev
// (erev = ±1 * mask, so W carries both the mask and the reversal sign;
//  |W| = w*mask is the denominator weight since w > 0.)
// sigmoid((v-mu)*sigma) = 1 / (1 + exp2(B - A*v))
// ---------------------------------------------------------------------------
__global__ void prep_pair(const float* __restrict__ sigma, const float* __restrict__ mu,
                          const float* __restrict__ w, const float* __restrict__ erev,
                          float4* __restrict__ P, int n)
{
    int i = blockIdx.x * 256 + threadIdx.x;
    if (i >= n) return;
    const float L2E = 1.4426950408889634f;
    float a = sigma[i] * L2E;
    P[i] = make_float4(a, mu[i] * a, w[i] * erev[i], 0.f);
}

__global__ void prep_vec(const float* __restrict__ gleak, const float* __restrict__ vleak,
                         const float* __restrict__ cm,
                         float* __restrict__ cmt, float* __restrict__ nb,
                         float* __restrict__ db, int n)
{
    int i = blockIdx.x * 256 + threadIdx.x;
    if (i >= n) return;
    float c6 = cm[i] * 6.f;          // cm_t = cm * ode_unfolds
    float gl = gleak[i];
    cmt[i] = c6;
    nb[i]  = gl * vleak[i];          // gleak*vleak  (numerator base)
    db[i]  = c6 + gl + 1e-8f;        // cm_t + gleak + EPS (denominator base)
}

// ---------------------------------------------------------------------------
// Layer 1: S=128 sensory, U=128 units. One block per batch element.
// 512 threads: uo = tid&127 (output unit), g = tid>>7 (4 groups of 32 inputs)
// ---------------------------------------------------------------------------
__global__ __launch_bounds__(512, 1) void ltc1(
    const float* __restrict__ x,                 // [64][512][128]
    const float* __restrict__ in_w, const float* __restrict__ in_b,   // [128]
    const float4* __restrict__ Ps,               // sensory packed [128*128]
    const float4* __restrict__ Pr,               // recurrent packed [128*128]
    const float* __restrict__ cmt, const float* __restrict__ nbv, const float* __restrict__ dbv,
    const float* __restrict__ ow, const float* __restrict__ ob,       // output map [128]
    float* __restrict__ h1)                      // [64][512][128]
{
    const int b   = blockIdx.x;
    const int tid = threadIdx.x;
    const int uo  = tid & (U1 - 1);
    const int g   = tid >> 7;           // 0..3, each covers 32 input units

    __shared__ float  v[U1];
    __shared__ float  ibuf[S1];
    __shared__ float2 red[4][U1];
    __shared__ float  nbs[U1], dbs[U1];

    float c_cmt = 0, c_nb = 0, c_db = 0, c_iw = 0, c_ib = 0, c_ow = 0, c_ob = 0;
    if (tid < U1) {
        v[tid] = 0.f;
        c_cmt = cmt[tid]; c_nb = nbv[tid]; c_db = dbv[tid];
        c_iw = in_w[tid]; c_ib = in_b[tid];
        c_ow = ow[tid];   c_ob = ob[tid];
    }
    const float* xb = x  + (size_t)b * T_STEPS * S1;
    float*       hb = h1 + (size_t)b * T_STEPS * U1;

    for (int t = 0; t < T_STEPS; ++t) {
        if (tid < S1) ibuf[tid] = fmaf(xb[t * S1 + tid], c_iw, c_ib);
        __syncthreads();

        // sensory partials (depend only on x_t)
        {
            float an = 0.f, ad = 0.f;
            const int s0 = g * 32;
            #pragma unroll 4
            for (int s2 = 0; s2 < 32; s2 += 4) {
                float4 iv = *reinterpret_cast<const float4*>(&ibuf[s0 + s2]);
                int base = (s0 + s2) * U1 + uo;
                float ivv[4] = {iv.x, iv.y, iv.z, iv.w};
                #pragma unroll
                for (int j = 0; j < 4; ++j) {
                    float4 p = Ps[base + j * U1];
                    float e = fast_exp2(p.y - p.x * ivv[j]);
                    float r = fast_rcp(1.f + e);
                    an = fmaf(p.z, r, an);
                    ad = fmaf(fabsf(p.z), r, ad);
                }
            }
            red[g][uo] = make_float2(an, ad);
        }
        __syncthreads();
        if (tid < U1) {
            float2 r0 = red[0][tid], r1 = red[1][tid], r2 = red[2][tid], r3 = red[3][tid];
            nbs[tid] = c_nb + ((r0.x + r1.x) + (r2.x + r3.x));
            dbs[tid] = c_db + ((r0.y + r1.y) + (r2.y + r3.y));
        }
        __syncthreads();

        for (int k = 0; k < NUNF; ++k) {
            float an = 0.f, ad = 0.f;
            const int s0 = g * 32;
            #pragma unroll 4
            for (int s2 = 0; s2 < 32; s2 += 4) {
                float4 vv = *reinterpret_cast<const float4*>(&v[s0 + s2]);
                int base = (s0 + s2) * U1 + uo;
                float vvv[4] = {vv.x, vv.y, vv.z, vv.w};
                #pragma unroll
                for (int j = 0; j < 4; ++j) {
                    float4 p = Pr[base + j * U1];
                    float e = fast_exp2(p.y - p.x * vvv[j]);
                    float r = fast_rcp(1.f + e);
                    an = fmaf(p.z, r, an);
                    ad = fmaf(fabsf(p.z), r, ad);
                }
            }
            red[g][uo] = make_float2(an, ad);
            __syncthreads();
            if (tid < U1) {
                float2 r0 = red[0][tid], r1 = red[1][tid], r2 = red[2][tid], r3 = red[3][tid];
                float wn = nbs[tid] + ((r0.x + r1.x) + (r2.x + r3.x));
                float wd = dbs[tid] + ((r0.y + r1.y) + (r2.y + r3.y));
                v[tid] = fmaf(c_cmt, v[tid], wn) * fast_rcp(wd);
            }
            __syncthreads();
        }
        if (tid < U1) hb[t * U1 + tid] = fmaf(v[tid], c_ow, c_ob);
    }
}

// ---------------------------------------------------------------------------
// Layer 2: S=128 sensory, U=256 units, motor=64, fused FC head.
// 512 threads: uo = tid&255, g = tid>>8 (2 groups of 128 inputs)
// ---------------------------------------------------------------------------
__global__ __launch_bounds__(512, 1) void ltc2(
    const float* __restrict__ h1,                // [64][512][128]
    const float* __restrict__ in_w, const float* __restrict__ in_b,   // [128]
    const float4* __restrict__ Ps,               // sensory packed [128*256]
    const float4* __restrict__ Pr,               // recurrent packed [256*256]
    const float* __restrict__ cmt, const float* __restrict__ nbv, const float* __restrict__ dbv,
    const float* __restrict__ ow, const float* __restrict__ ob,       // [64]
    const float* __restrict__ fcw, const float* __restrict__ fcb,     // [64*64],[64]
    float* __restrict__ out)                     // [64][512][64]
{
    const int b   = blockIdx.x;
    const int tid = threadIdx.x;
    const int uo  = tid & (U2 - 1);
    const int g   = tid >> 8;           // 0..1

    __shared__ float  v[U2];
    __shared__ float  ibuf[S2];
    __shared__ float2 red[2][U2];
    __shared__ float  nbs[U2], dbs[U2];
    __shared__ float  fcwT[64 * 64];
    __shared__ float  h2buf[64];

    // preload fc_w transposed: fcwT[k][o] = fc_w[o][k]
    for (int idx = tid; idx < 64 * 64; idx += 512) {
        int o = idx >> 6, k = idx & 63;
        fcwT[k * 64 + o] = fcw[idx];
    }

    float c_cmt = 0, c_nb = 0, c_db = 0;
    if (tid < U2) {
        v[tid] = 0.f;
        c_cmt = cmt[tid]; c_nb = nbv[tid]; c_db = dbv[tid];
    }
    float c_iw = 0, c_ib = 0;
    if (tid < S2) { c_iw = in_w[tid]; c_ib = in_b[tid]; }
    float c_ow = 0, c_ob = 0, c_fcb = 0;
    if (tid < 64) { c_ow = ow[tid]; c_ob = ob[tid]; c_fcb = fcb[tid]; }

    const float* hb = h1  + (size_t)b * T_STEPS * S2;
    float*       op = out + (size_t)b * T_STEPS * 64;
    __syncthreads();

    for (int t = 0; t < T_STEPS; ++t) {
        if (tid < S2) ibuf[tid] = fmaf(hb[t * S2 + tid], c_iw, c_ib);
        __syncthreads();

        // sensory partials: g covers s in [g*64, g*64+64)
        {
            float an = 0.f, ad = 0.f;
            const int s0 = g * 64;
            #pragma unroll 4
            for (int s2 = 0; s2 < 64; s2 += 4) {
                float4 iv = *reinterpret_cast<const float4*>(&ibuf[s0 + s2]);
                int base = (s0 + s2) * U2 + uo;
                float ivv[4] = {iv.x, iv.y, iv.z, iv.w};
                #pragma unroll
                for (int j = 0; j < 4; ++j) {
                    float4 p = Ps[base + j * U2];
                    float e = fast_exp2(p.y - p.x * ivv[j]);
                    float r = fast_rcp(1.f + e);
                    an = fmaf(p.z, r, an);
                    ad = fmaf(fabsf(p.z), r, ad);
                }
            }
            red[g][uo] = make_float2(an, ad);
        }
        __syncthreads();
        if (tid < U2) {
            float2 r0 = red[0][tid], r1 = red[1][tid];
            nbs[tid] = c_nb + r0.x + r1.x;
            dbs[tid] = c_db + r0.y + r1.y;
        }
        __syncthreads();

        for (int k = 0; k < NUNF; ++k) {
            float an = 0.f, ad = 0.f;
            const int s0 = g * 128;
            #pragma unroll 4
            for (int s2 = 0; s2 < 128; s2 += 4) {
                float4 vv = *reinterpret_cast<const float4*>(&v[s0 + s2]);
                int base = (s0 + s2) * U2 + uo;
                float vvv[4] = {vv.x, vv.y, vv.z, vv.w};
                #pragma unroll
                for (int j = 0; j < 4; ++j) {
                    float4 p = Pr[base + j * U2];
                    float e = fast_exp2(p.y - p.x * vvv[j]);
                    float r = fast_rcp(1.f + e);
                    an = fmaf(p.z, r, an);
                    ad = fmaf(fabsf(p.z), r, ad);
                }
            }
            red[g][uo] = make_float2(an, ad);
            __syncthreads();
            if (tid < U2) {
                float2 r0 = red[0][tid], r1 = red[1][tid];
                float wn = nbs[tid] + r0.x + r1.x;
                float wd = dbs[tid] + r0.y + r1.y;
                v[tid] = fmaf(c_cmt, v[tid], wn) * fast_rcp(wd);
            }
            __syncthreads();
        }

        // motor map + fused FC head
        if (tid < 64) h2buf[tid] = fmaf(v[tid], c_ow, c_ob);
        __syncthreads();
        if (tid < 64) {
            float acc = c_fcb;
            #pragma unroll 16
            for (int kk = 0; kk < 64; ++kk)
                acc = fmaf(h2buf[kk], fcwT[kk * 64 + tid], acc);
            op[t * 64 + tid] = acc;
        }
        __syncthreads();
    }
}

// ---------------------------------------------------------------------------
extern "C" void kernel_launch(void* const* d_in, const int* in_sizes, int n_in,
                              void* d_out, int out_size, void* d_ws, size_t ws_size,
                              hipStream_t stream)
{
    (void)in_sizes; (void)n_in; (void)out_size; (void)ws_size;

    const float* x      = (const float*)d_in[0];
    const float* l1_iw  = (const float*)d_in[1];
    const float* l1_ib  = (const float*)d_in[2];
    const float* l1_sw  = (const float*)d_in[3];
    const float* l1_ss  = (const float*)d_in[4];
    const float* l1_smu = (const float*)d_in[5];
    const float* l1_se  = (const float*)d_in[6];
    const float* l1_w   = (const float*)d_in[8];
    const float* l1_sg  = (const float*)d_in[9];
    const float* l1_mu  = (const float*)d_in[10];
    const float* l1_er  = (const float*)d_in[11];
    const float* l1_gl  = (const float*)d_in[13];
    const float* l1_vl  = (const float*)d_in[14];
    const float* l1_cm  = (const float*)d_in[15];
    const float* l1_ow  = (const float*)d_in[16];
    const float* l1_ob  = (const float*)d_in[17];
    const float* l2_iw  = (const float*)d_in[18];
    const float* l2_ib  = (const float*)d_in[19];
    const float* l2_sw  = (const float*)d_in[20];
    const float* l2_ss  = (const float*)d_in[21];
    const float* l2_smu = (const float*)d_in[22];
    const float* l2_se  = (const float*)d_in[23];
    const float* l2_w   = (const float*)d_in[25];
    const float* l2_sg  = (const float*)d_in[26];
    const float* l2_mu  = (const float*)d_in[27];
    const float* l2_er  = (const float*)d_in[28];
    const float* l2_gl  = (const float*)d_in[30];
    const float* l2_vl  = (const float*)d_in[31];
    const float* l2_cm  = (const float*)d_in[32];
    const float* l2_ow  = (const float*)d_in[33];
    const float* l2_ob  = (const float*)d_in[34];
    const float* fcw    = (const float*)d_in[35];
    const float* fcb    = (const float*)d_in[36];

    float* W = (float*)d_ws;
    size_t off = 0;
    float* h1 = W + off;        off += (size_t)B_SZ * T_STEPS * U1;   // 4,194,304 f
    float4* P1s = (float4*)(W + off); off += (size_t)S1 * U1 * 4;     // packed sensory L1
    float4* P1r = (float4*)(W + off); off += (size_t)U1 * U1 * 4;
    float4* P2s = (float4*)(W + off); off += (size_t)S2 * U2 * 4;
    float4* P2r = (float4*)(W + off); off += (size_t)U2 * U2 * 4;
    float* cmt1 = W + off; off += U1;
    float* nb1  = W + off; off += U1;
    float* db1  = W + off; off += U1;
    float* cmt2 = W + off; off += U2;
    float* nb2  = W + off; off += U2;
    float* db2  = W + off; off += U2;

    prep_pair<<<(S1 * U1 + 255) / 256, 256, 0, stream>>>(l1_ss, l1_smu, l1_sw, l1_se, P1s, S1 * U1);
    prep_pair<<<(U1 * U1 + 255) / 256, 256, 0, stream>>>(l1_sg, l1_mu,  l1_w,  l1_er, P1r, U1 * U1);
    prep_pair<<<(S2 * U2 + 255) / 256, 256, 0, stream>>>(l2_ss, l2_smu, l2_sw, l2_se, P2s, S2 * U2);
    prep_pair<<<(U2 * U2 + 255) / 256, 256, 0, stream>>>(l2_sg, l2_mu,  l2_w,  l2_er, P2r, U2 * U2);
    prep_vec<<<1, 256, 0, stream>>>(l1_gl, l1_vl, l1_cm, cmt1, nb1, db1, U1);
    prep_vec<<<1, 256, 0, stream>>>(l2_gl, l2_vl, l2_cm, cmt2, nb2, db2, U2);

    ltc1<<<B_SZ, 512, 0, stream>>>(x, l1_iw, l1_ib, P1s, P1r, cmt1, nb1, db1, l1_ow, l1_ob, h1);
    ltc2<<<B_SZ, 512, 0, stream>>>(h1, l2_iw, l2_ib, P2s, P2r, cmt2, nb2, db2, l2_ow, l2_ob,
                                   fcw, fcb, (float*)d_out);
}